// Round 3
// baseline (11019.144 us; speedup 1.0000x reference)
//
#include <hip/hip_runtime.h>
#include <cmath>

#define B_ 1024
#define T_ 75
#define IN_ 768
#define H_ 512
#define G_ 2048
#define R_ 16          // batch rows per persistent block

#define EPSF 1e-15f
#define MAXN 0.99999f

typedef __bf16 bf16_t;
typedef bf16_t bf16x8 __attribute__((ext_vector_type(8)));
typedef float f32x4 __attribute__((ext_vector_type(4)));
typedef unsigned short u16;
typedef u16 u16x8 __attribute__((ext_vector_type(8)));

// ---------------- scalar helpers ----------------

__device__ inline float sigmoidf_(float x) { return 1.0f / (1.0f + expf(-x)); }

__device__ inline u16 f2bf(float f) {  // RNE float->bf16
    unsigned u = __builtin_bit_cast(unsigned, f);
    u = u + 0x7FFFu + ((u >> 16) & 1u);
    return (u16)(u >> 16);
}
__device__ inline float bf2f(u16 h) {
    return __builtin_bit_cast(float, (unsigned)h << 16);
}

// logmap0 o proj o expmap0 composite scale
__device__ inline float tangentize_scale(float n) {
    float n1 = fmaxf(n, EPSF);
    float m = fminf(tanhf(n1), MAXN);
    return atanhf(m) / n1;
}
__device__ inline float expproj_scale(float n) {
    float n1 = fmaxf(n, EPSF);
    return fminf(tanhf(n1), MAXN) / n1;
}

__device__ inline float blockReduceSum(float v) {
    __shared__ float sm[8];
    __syncthreads();
    #pragma unroll
    for (int off = 32; off > 0; off >>= 1) v += __shfl_down(v, off, 64);
    int w = threadIdx.x >> 6, lane = threadIdx.x & 63;
    if (lane == 0) sm[w] = v;
    __syncthreads();
    int nw = (blockDim.x + 63) >> 6;
    if (threadIdx.x == 0) {
        float r = sm[0];
        for (int i = 1; i < nw; ++i) r += sm[i];
        sm[0] = r;
    }
    __syncthreads();
    return sm[0];
}

// ---------------- precompute kernels ----------------

__global__ void cvt_f32_bf16(const float* __restrict__ s, u16* __restrict__ d, int n) {
    int i = (blockIdx.x * 256 + threadIdx.x) * 4;
    if (i < n) {
        float4 f = *reinterpret_cast<const float4*>(s + i);
        d[i + 0] = f2bf(f.x); d[i + 1] = f2bf(f.y);
        d[i + 2] = f2bf(f.z); d[i + 3] = f2bf(f.w);
    }
}

// sentb[t][b][k] = bf16( sent[b][t][k] * tangentize_scale(||sent[b][t]||) )
__global__ __launch_bounds__(256) void prep_sentb(const float* __restrict__ sent,
                                                  u16* __restrict__ sentb) {
    int bid = blockIdx.x;            // = b*75 + t
    int b = bid / T_, t = bid - b * T_;
    const float* src = sent + (size_t)bid * IN_;
    float v[3]; float ss = 0.f;
    #pragma unroll
    for (int e = 0; e < 3; ++e) { v[e] = src[threadIdx.x + e * 256]; ss += v[e] * v[e]; }
    float tot = blockReduceSum(ss);
    float sc = tangentize_scale(sqrtf(tot));
    u16* dst = sentb + ((size_t)t * B_ + b) * IN_;
    #pragma unroll
    for (int e = 0; e < 3; ++e) dst[threadIdx.x + e * 256] = f2bf(v[e] * sc);
}

// fallback: xscale[b*T+t]
__global__ __launch_bounds__(256) void xscale_kernel(const float* __restrict__ x,
                                                     float* __restrict__ xscale) {
    int row = blockIdx.x;
    const float* p = x + (size_t)row * IN_;
    float s = 0.f;
    for (int k = threadIdx.x; k < IN_; k += 256) { float v = p[k]; s += v * v; }
    float tot = blockReduceSum(s);
    if (threadIdx.x == 0) xscale[row] = tangentize_scale(sqrtf(tot));
}

// tf = proj(expmap0(time_feats)) rowwise over T
__global__ void tf_kernel(const float* __restrict__ x, float* __restrict__ tf) {
    int b = blockIdx.x;
    float v = (threadIdx.x < T_) ? x[(size_t)b * T_ + threadIdx.x] : 0.f;
    float tot = blockReduceSum(v * v);
    float s = expproj_scale(sqrtf(tot));
    if (threadIdx.x < T_) tf[(size_t)b * T_ + threadIdx.x] = s * v;
}

// ---------------- XU GEMM: XU[t*1024+b][g] = xt @ U_all^T + b_U + b_all ----------------
// M=76800 (t-major), N=2048, K=768. 128x128 tile, 256 thr, bf16 MFMA.
template<int F32SRC>
__global__ __launch_bounds__(256) void xu_gemm(const void* __restrict__ Asrc,
    const float* __restrict__ xscale, const u16* __restrict__ W,
    const float* __restrict__ b1, const float* __restrict__ b2, u16* __restrict__ C)
{
    __shared__ __align__(16) unsigned char As[128 * 128];
    __shared__ __align__(16) unsigned char Ws[128 * 128];
    int bid = (int)blockIdx.x;
    bid = (bid & 7) * ((int)gridDim.x >> 3) + (bid >> 3);   // 9600 % 8 == 0: bijective
    const int bn = (bid % 16) * 128;
    const int bm = (bid / 16) * 128;
    const int tq = bm >> 10;          // t (constant per block)
    const int b0 = bm & 1023;

    const int tid = threadIdx.x;
    const int lane = tid & 63;
    const int wid = tid >> 6;
    const int wr = wid >> 1, wc = wid & 1;
    const int l15 = lane & 15, l4 = lane >> 4;

    f32x4 acc[4][4] = {};

    for (int k0 = 0; k0 < IN_; k0 += 64) {
        __syncthreads();
        #pragma unroll
        for (int c = 0; c < 4; ++c) {           // A tile 128 x 64
            int ch = c * 256 + tid;
            int r = ch >> 3, q = ch & 7;
            unsigned off = (unsigned)(r * 128 + ((q ^ (r & 7)) * 16));
            if (F32SRC) {
                int b = b0 + r;
                const float* src = (const float*)Asrc + ((size_t)b * T_ + tq) * IN_ + k0 + q * 8;
                float rs = xscale[(size_t)b * T_ + tq];
                float4 f0 = *reinterpret_cast<const float4*>(src);
                float4 f1 = *reinterpret_cast<const float4*>(src + 4);
                u16x8 v;
                v[0] = f2bf(f0.x * rs); v[1] = f2bf(f0.y * rs);
                v[2] = f2bf(f0.z * rs); v[3] = f2bf(f0.w * rs);
                v[4] = f2bf(f1.x * rs); v[5] = f2bf(f1.y * rs);
                v[6] = f2bf(f1.z * rs); v[7] = f2bf(f1.w * rs);
                *reinterpret_cast<u16x8*>(As + off) = v;
            } else {
                const u16* src = (const u16*)Asrc + (size_t)(bm + r) * IN_ + k0 + q * 8;
                *reinterpret_cast<u16x8*>(As + off) = *reinterpret_cast<const u16x8*>(src);
            }
        }
        #pragma unroll
        for (int c = 0; c < 4; ++c) {           // W tile 128 x 64
            int ch = c * 256 + tid;
            int r = ch >> 3, q = ch & 7;
            unsigned off = (unsigned)(r * 128 + ((q ^ (r & 7)) * 16));
            const u16* src = W + (size_t)(bn + r) * IN_ + k0 + q * 8;
            *reinterpret_cast<u16x8*>(Ws + off) = *reinterpret_cast<const u16x8*>(src);
        }
        __syncthreads();
        #pragma unroll
        for (int ks = 0; ks < 2; ++ks) {
            bf16x8 af[4], bf[4];
            #pragma unroll
            for (int m = 0; m < 4; ++m) {
                int r = wr * 64 + m * 16 + l15;
                af[m] = *reinterpret_cast<const bf16x8*>(As + r * 128 + (((ks * 4 + l4) ^ (r & 7)) * 16));
            }
            #pragma unroll
            for (int n = 0; n < 4; ++n) {
                int r = wc * 64 + n * 16 + l15;
                bf[n] = *reinterpret_cast<const bf16x8*>(Ws + r * 128 + (((ks * 4 + l4) ^ (r & 7)) * 16));
            }
            #pragma unroll
            for (int m = 0; m < 4; ++m)
                #pragma unroll
                for (int n = 0; n < 4; ++n)
                    acc[m][n] = __builtin_amdgcn_mfma_f32_16x16x32_bf16(af[m], bf[n], acc[m][n], 0, 0, 0);
        }
    }

    #pragma unroll
    for (int m = 0; m < 4; ++m)
        #pragma unroll
        for (int n = 0; n < 4; ++n) {
            int col = bn + wc * 64 + n * 16 + l15;
            float bb = b1[col] + b2[col];
            #pragma unroll
            for (int v = 0; v < 4; ++v) {
                int row = bm + wr * 64 + m * 16 + l4 * 4 + v;
                C[(size_t)row * G_ + col] = f2bf(acc[m][n][v] + bb);
            }
        }
}

// ---------------- THE persistent kernel: encoder 75 steps + proj + span + decoder 10 steps ----
// 64 blocks x 1024 threads (16 waves). Block owns 16 batch rows; states in LDS (bf16,
// XOR-swizzled); weights streamed L2->VGPR as MFMA B-fragments; gates never leave LDS.

__global__ __launch_bounds__(1024) void persistent(
    const u16* __restrict__ XU,       // [75][1024][2048] bf16 (includes b_U + b_all)
    const float* __restrict__ tf_g,   // [1024][75]
    const u16* __restrict__ Wall,     // [2048][512]
    const u16* __restrict__ Wd,       // [512][512]
    const float* __restrict__ bd,
    const u16* __restrict__ Wih,      // [2048][768]
    const u16* __restrict__ Whh,      // [2048][512]
    const float* __restrict__ b_ih, const float* __restrict__ b_hh,
    const u16* __restrict__ Wfcin,    // [768][512]
    const float* __restrict__ b_fcin,
    const float* __restrict__ Wfco,   // f32 [2][512]
    const float* __restrict__ b_fco,
    const float* __restrict__ Wspan,  // f32 [4][512]
    const float* __restrict__ bspan,
    float* __restrict__ out)
{
    __shared__ u16 ht[R_ * 512];      // 16 KB  (tangent h, bf16)
    __shared__ u16 ct[R_ * 512];      // 16 KB
    __shared__ u16 gt[R_ * 2048];     // 64 KB  (gates)
    __shared__ u16 inp[R_ * 768];     // 24 KB  (cs1 in encoder / decoder input)
    __shared__ float tfl[R_ * T_];    // 4.8 KB
    __shared__ float lg[64];

    const int tid = threadIdx.x;
    const int r0 = blockIdx.x * R_;
    const int w = __builtin_amdgcn_readfirstlane(tid >> 6);   // wave id 0..15 (uniform)
    const int lane = tid & 63;
    const int l15 = lane & 15, l4 = lane >> 4;
    const int aoff = l4 * 8;                 // k sub-offset in a fragment
    const int asw = (l15 & 7) << 3;          // A-frag row swizzle

    for (int i = tid; i < R_ * 512; i += 1024) { ht[i] = 0; ct[i] = 0; }
    for (int i = tid; i < R_ * T_; i += 1024) tfl[i] = tf_g[(size_t)r0 * T_ + i];
    __syncthreads();

    // ================= encoder =================
    for (int t = 0; t < T_; ++t) {
        // wave w: 8 gate tiles (n0=(w*8+i)*16, A=ht) + 2 cs1 tiles (n0=(w*2+i)*16, A=ct)
        f32x4 ag[8] = {};
        f32x4 ac2[2] = {};
        for (int ks = 0; ks < 16; ++ks) {
            int ko = ks * 32 + aoff;
            bf16x8 ah = *reinterpret_cast<const bf16x8*>(&ht[l15 * 512 + (ko ^ asw)]);
            bf16x8 av = *reinterpret_cast<const bf16x8*>(&ct[l15 * 512 + (ko ^ asw)]);
            bf16x8 bg[8], bc[2];
            #pragma unroll
            for (int i = 0; i < 8; ++i)
                bg[i] = *reinterpret_cast<const bf16x8*>(Wall + (size_t)((w * 8 + i) * 16 + l15) * 512 + ko);
            #pragma unroll
            for (int i = 0; i < 2; ++i)
                bc[i] = *reinterpret_cast<const bf16x8*>(Wd + (size_t)((w * 2 + i) * 16 + l15) * 512 + ko);
            #pragma unroll
            for (int i = 0; i < 8; ++i)
                ag[i] = __builtin_amdgcn_mfma_f32_16x16x32_bf16(ah, bg[i], ag[i], 0, 0, 0);
            #pragma unroll
            for (int i = 0; i < 2; ++i)
                ac2[i] = __builtin_amdgcn_mfma_f32_16x16x32_bf16(av, bc[i], ac2[i], 0, 0, 0);
        }
        // epilogue -> LDS
        const u16* XUt = XU + ((size_t)t * B_ + r0) * G_;
        #pragma unroll
        for (int i = 0; i < 8; ++i) {
            int col = (w * 8 + i) * 16 + l15;
            #pragma unroll
            for (int v = 0; v < 4; ++v) {
                int row = l4 * 4 + v;
                float val = ag[i][v] + bf2f(XUt[(size_t)row * G_ + col]);
                gt[row * 2048 + (col ^ ((row & 7) << 3))] = f2bf(sigmoidf_(val));
            }
        }
        #pragma unroll
        for (int i = 0; i < 2; ++i) {
            int col = (w * 2 + i) * 16 + l15;
            float bb = bd[col];
            #pragma unroll
            for (int v = 0; v < 4; ++v) {
                int row = l4 * 4 + v;
                inp[row * 768 + (col ^ ((row & 7) << 3))] = f2bf(tanhf(ac2[i][v] + bb));
            }
        }
        __syncthreads();
        // pointwise: wave w owns row w
        {
            const int r = w;
            const int j0 = lane * 8;
            const int sw = (r & 7) << 3;
            int js = j0 ^ sw;
            u16x8 f8 = *reinterpret_cast<const u16x8*>(&gt[r * 2048 + js]);
            u16x8 i8 = *reinterpret_cast<const u16x8*>(&gt[r * 2048 + 512 + js]);
            u16x8 o8 = *reinterpret_cast<const u16x8*>(&gt[r * 2048 + 1024 + js]);
            u16x8 m8 = *reinterpret_cast<const u16x8*>(&gt[r * 2048 + 1536 + js]);
            u16x8 c18 = *reinterpret_cast<const u16x8*>(&inp[r * 768 + js]);
            u16x8 ct8 = *reinterpret_cast<const u16x8*>(&ct[r * 512 + js]);
            float ts = tfl[r * T_ + t];
            float cn[8], hn[8], nc = 0.f, nh = 0.f;
            #pragma unroll
            for (int e = 0; e < 8; ++e) {
                float f = bf2f(f8[e]), ii = bf2f(i8[e]), o = bf2f(o8[e]), cm = bf2f(m8[e]);
                float c1 = bf2f(c18[e]), co = bf2f(ct8[e]);
                float cadj = co - c1 + c1 * ts;
                float c = f * cadj + ii * cm;
                float h = o * tanhf(c);
                cn[e] = c; hn[e] = h; nc += c * c; nh += h * h;
            }
            #pragma unroll
            for (int off = 32; off > 0; off >>= 1) {
                nc += __shfl_xor(nc, off); nh += __shfl_xor(nh, off);
            }
            float sc = tangentize_scale(sqrtf(nc));
            float sh = tangentize_scale(sqrtf(nh));
            u16x8 cw, hw;
            #pragma unroll
            for (int e = 0; e < 8; ++e) { cw[e] = f2bf(cn[e] * sc); hw[e] = f2bf(hn[e] * sh); }
            *reinterpret_cast<u16x8*>(&ct[r * 512 + js]) = cw;
            *reinterpret_cast<u16x8*>(&ht[r * 512 + js]) = hw;
        }
        __syncthreads();
    }

    // ================= proj (hx, cx) =================
    {
        const int r = w;
        const int j0 = lane * 8;
        const int js = j0 ^ ((r & 7) << 3);
        u16x8 h8 = *reinterpret_cast<const u16x8*>(&ht[r * 512 + js]);
        u16x8 c8 = *reinterpret_cast<const u16x8*>(&ct[r * 512 + js]);
        float sh = 0.f, sc = 0.f;
        #pragma unroll
        for (int e = 0; e < 8; ++e) {
            float h = bf2f(h8[e]), c = bf2f(c8[e]);
            sh += h * h; sc += c * c;
        }
        #pragma unroll
        for (int off = 32; off > 0; off >>= 1) {
            sh += __shfl_xor(sh, off); sc += __shfl_xor(sc, off);
        }
        float nh = fmaxf(sqrtf(sh), EPSF), ncv = fmaxf(sqrtf(sc), EPSF);
        float fh = nh > MAXN ? MAXN / nh : 1.f;
        float fc = ncv > MAXN ? MAXN / ncv : 1.f;
        u16x8 hw, cw;
        #pragma unroll
        for (int e = 0; e < 8; ++e) {
            hw[e] = f2bf(bf2f(h8[e]) * fh);
            cw[e] = f2bf(bf2f(c8[e]) * fc);
        }
        *reinterpret_cast<u16x8*>(&ht[r * 512 + js]) = hw;
        *reinterpret_cast<u16x8*>(&ct[r * 512 + js]) = cw;
    }
    __syncthreads();

    // ================= span softmax =================
    {
        int p = tid >> 4;                // 0..63 = 16 rows x 4 cols
        int row = p >> 2, col = p & 3;
        int k0 = (tid & 15) * 32;
        int sw = (row & 7) << 3;
        float s = 0.f;
        for (int e = 0; e < 32; ++e) {
            int k = k0 + e;
            s += bf2f(ht[row * 512 + (k ^ sw)]) * Wspan[col * 512 + k];
        }
        #pragma unroll
        for (int off = 8; off > 0; off >>= 1) s += __shfl_down(s, off);
        if ((lane & 15) == 0) lg[p] = s + bspan[col];
    }
    __syncthreads();
    if (tid < 16) {
        float a = lg[tid * 4], b = lg[tid * 4 + 1], c = lg[tid * 4 + 2], d = lg[tid * 4 + 3];
        float m = fmaxf(fmaxf(a, b), fmaxf(c, d));
        float ea = expf(a - m), eb = expf(b - m), ec = expf(c - m), ed = expf(d - m);
        float den = ea + eb + ec + ed;
        float* o = out + (size_t)(r0 + tid) * 4;
        o[0] = ea / den; o[1] = eb / den; o[2] = ec / den; o[3] = ed / den;
    }
    __syncthreads();
    for (int i = tid; i < R_ * 768; i += 1024) inp[i] = 0;   // inp0 = zeros
    __syncthreads();

    // ================= decoder =================
    for (int s = 0; s < 10; ++s) {
        // gates: 8 tiles/wave over N=2048; K = 768 (inp) + 512 (h)
        f32x4 ag[8] = {};
        for (int ks = 0; ks < 24; ++ks) {
            int ko = ks * 32 + aoff;
            bf16x8 ax = *reinterpret_cast<const bf16x8*>(&inp[l15 * 768 + (ko ^ asw)]);
            bf16x8 bv[8];
            #pragma unroll
            for (int i = 0; i < 8; ++i)
                bv[i] = *reinterpret_cast<const bf16x8*>(Wih + (size_t)((w * 8 + i) * 16 + l15) * 768 + ko);
            #pragma unroll
            for (int i = 0; i < 8; ++i)
                ag[i] = __builtin_amdgcn_mfma_f32_16x16x32_bf16(ax, bv[i], ag[i], 0, 0, 0);
        }
        for (int ks = 0; ks < 16; ++ks) {
            int ko = ks * 32 + aoff;
            bf16x8 ax = *reinterpret_cast<const bf16x8*>(&ht[l15 * 512 + (ko ^ asw)]);
            bf16x8 bv[8];
            #pragma unroll
            for (int i = 0; i < 8; ++i)
                bv[i] = *reinterpret_cast<const bf16x8*>(Whh + (size_t)((w * 8 + i) * 16 + l15) * 512 + ko);
            #pragma unroll
            for (int i = 0; i < 8; ++i)
                ag[i] = __builtin_amdgcn_mfma_f32_16x16x32_bf16(ax, bv[i], ag[i], 0, 0, 0);
        }
        #pragma unroll
        for (int i = 0; i < 8; ++i) {
            int col = (w * 8 + i) * 16 + l15;
            float bb = b_ih[col] + b_hh[col];
            #pragma unroll
            for (int v = 0; v < 4; ++v) {
                int row = l4 * 4 + v;
                gt[row * 2048 + (col ^ ((row & 7) << 3))] = f2bf(ag[i][v] + bb);
            }
        }
        __syncthreads();
        // pointwise LSTM (torch order i,f,g,o): wave w = row w
        {
            const int r = w;
            const int j0 = lane * 8;
            const int js = j0 ^ ((r & 7) << 3);
            u16x8 i8 = *reinterpret_cast<const u16x8*>(&gt[r * 2048 + js]);
            u16x8 f8 = *reinterpret_cast<const u16x8*>(&gt[r * 2048 + 512 + js]);
            u16x8 g8 = *reinterpret_cast<const u16x8*>(&gt[r * 2048 + 1024 + js]);
            u16x8 o8 = *reinterpret_cast<const u16x8*>(&gt[r * 2048 + 1536 + js]);
            u16x8 c8 = *reinterpret_cast<const u16x8*>(&ct[r * 512 + js]);
            u16x8 cw, hw;
            #pragma unroll
            for (int e = 0; e < 8; ++e) {
                float ii = sigmoidf_(bf2f(i8[e]));
                float ff = sigmoidf_(bf2f(f8[e]));
                float gg = tanhf(bf2f(g8[e]));
                float oo = sigmoidf_(bf2f(o8[e]));
                float c = ff * bf2f(c8[e]) + ii * gg;
                float h = oo * tanhf(c);
                cw[e] = f2bf(c); hw[e] = f2bf(h);
            }
            *reinterpret_cast<u16x8*>(&ct[r * 512 + js]) = cw;
            *reinterpret_cast<u16x8*>(&ht[r * 512 + js]) = hw;
        }
        __syncthreads();
        // out2 logits (reads new h)
        if (tid < 512) {
            int p = tid >> 4;            // 0..31 = 16 rows x 2 cols
            int row = p >> 1, col = p & 1;
            int k0 = (tid & 15) * 32;
            int sw = (row & 7) << 3;
            float sum = 0.f;
            for (int e = 0; e < 32; ++e) {
                int k = k0 + e;
                sum += bf2f(ht[row * 512 + (k ^ sw)]) * Wfco[col * 512 + k];
            }
            #pragma unroll
            for (int off = 8; off > 0; off >>= 1) sum += __shfl_down(sum, off);
            if ((lane & 15) == 0) lg[p] = sum + b_fco[col];
        }
        // fc_in: 3 tiles/wave over N=768, K=512, A = h
        f32x4 af2[3] = {};
        for (int ks = 0; ks < 16; ++ks) {
            int ko = ks * 32 + aoff;
            bf16x8 ax = *reinterpret_cast<const bf16x8*>(&ht[l15 * 512 + (ko ^ asw)]);
            bf16x8 bv[3];
            #pragma unroll
            for (int i = 0; i < 3; ++i)
                bv[i] = *reinterpret_cast<const bf16x8*>(Wfcin + (size_t)((w * 3 + i) * 16 + l15) * 512 + ko);
            #pragma unroll
            for (int i = 0; i < 3; ++i)
                af2[i] = __builtin_amdgcn_mfma_f32_16x16x32_bf16(ax, bv[i], af2[i], 0, 0, 0);
        }
        __syncthreads();   // gt/inp consumers done; lg written
        #pragma unroll
        for (int i = 0; i < 3; ++i) {
            int col = (w * 3 + i) * 16 + l15;
            float bb = b_fcin[col];
            #pragma unroll
            for (int v = 0; v < 4; ++v) {
                int row = l4 * 4 + v;
                inp[row * 768 + (col ^ ((row & 7) << 3))] = f2bf(fmaxf(af2[i][v] + bb, 0.f));
            }
        }
        if (tid < 16) {
            float a = lg[tid * 2], b = lg[tid * 2 + 1];
            float m = fmaxf(a, b);
            float ea = expf(a - m), eb = expf(b - m);
            float den = ea + eb;
            float* o = out + 4096 + (size_t)(r0 + tid) * 20 + s * 2;
            o[0] = ea / den; o[1] = eb / den;
        }
        __syncthreads();   // inp visible for next step
    }
}

// ---------------- launch ----------------

extern "C" void kernel_launch(void* const* d_in, const int* in_sizes, int n_in,
                              void* d_out, int out_size, void* d_ws, size_t ws_size,
                              hipStream_t stream) {
    (void)in_sizes; (void)n_in; (void)out_size;
    const float* sent    = (const float*)d_in[0];
    const float* timef   = (const float*)d_in[1];
    const float* Wd      = (const float*)d_in[2];
    const float* bd      = (const float*)d_in[3];
    const float* W_all   = (const float*)d_in[4];
    const float* b_all   = (const float*)d_in[5];
    const float* U_all   = (const float*)d_in[6];
    const float* b_U     = (const float*)d_in[7];
    const float* W_ih    = (const float*)d_in[8];
    const float* b_ih    = (const float*)d_in[9];
    const float* W_hh    = (const float*)d_in[10];
    const float* b_hh    = (const float*)d_in[11];
    const float* W_fc_in = (const float*)d_in[12];
    const float* b_fc_in = (const float*)d_in[13];
    const float* W_fc_out= (const float*)d_in[14];
    const float* b_fc_out= (const float*)d_in[15];
    const float* W_span  = (const float*)d_in[16];
    const float* b_span  = (const float*)d_in[17];
    float* out = (float*)d_out;

    char* ws = (char*)d_ws;
    size_t off = 0;
    auto alloc = [&](size_t bytes) -> void* {
        void* p = ws + off; off = (off + bytes + 255) & ~(size_t)255; return p;
    };
    float* tf     = (float*)alloc((size_t)B_ * T_ * 4);
    u16* Wall_b   = (u16*)alloc((size_t)G_ * H_ * 2);
    u16* Uall_b   = (u16*)alloc((size_t)G_ * IN_ * 2);
    u16* Wd_b     = (u16*)alloc((size_t)H_ * H_ * 2);
    u16* Wih_b    = (u16*)alloc((size_t)G_ * IN_ * 2);
    u16* Whh_b    = (u16*)alloc((size_t)G_ * H_ * 2);
    u16* Wfcin_b  = (u16*)alloc((size_t)IN_ * H_ * 2);
    float* xscale = (float*)alloc((size_t)B_ * T_ * 4);
    u16* XU       = (u16*)alloc((size_t)B_ * T_ * G_ * 2);
    size_t off_noprep = off;
    u16* sentb    = (u16*)alloc((size_t)B_ * T_ * IN_ * 2);
    bool pathA = (off <= ws_size);
    (void)off_noprep;

    auto cvt = [&](const float* s, u16* d, int n) {
        cvt_f32_bf16<<<(n / 4 + 255) / 256, 256, 0, stream>>>(s, d, n);
    };
    cvt(W_all, Wall_b, G_ * H_);
    cvt(U_all, Uall_b, G_ * IN_);
    cvt(Wd, Wd_b, H_ * H_);
    cvt(W_ih, Wih_b, G_ * IN_);
    cvt(W_hh, Whh_b, G_ * H_);
    cvt(W_fc_in, Wfcin_b, IN_ * H_);

    tf_kernel<<<B_, 128, 0, stream>>>(timef, tf);

    if (pathA) {
        prep_sentb<<<B_ * T_, 256, 0, stream>>>(sent, sentb);
        xu_gemm<0><<<(B_ * T_ / 128) * (G_ / 128), 256, 0, stream>>>(
            sentb, nullptr, Uall_b, b_all, b_U, XU);
    } else {
        xscale_kernel<<<B_ * T_, 256, 0, stream>>>(sent, xscale);
        xu_gemm<1><<<(B_ * T_ / 128) * (G_ / 128), 256, 0, stream>>>(
            sent, xscale, Uall_b, b_all, b_U, XU);
    }

    persistent<<<B_ / R_, 1024, 0, stream>>>(
        XU, tf, Wall_b, Wd_b, bd, Wih_b, Whh_b, b_ih, b_hh,
        Wfcin_b, b_fc_in, W_fc_out, b_fc_out, W_span, b_span, out);
}

// Round 4
// 5942.536 us; speedup vs baseline: 1.8543x; 1.8543x over previous
//
#include <hip/hip_runtime.h>
#include <cmath>

#define B_ 1024
#define T_ 75
#define IN_ 768
#define H_ 512
#define G_ 2048
#define GRIDN 256

#define EPSF 1e-15f
#define MAXN 0.99999f

typedef __bf16 bf16_t;
typedef bf16_t bf16x8 __attribute__((ext_vector_type(8)));
typedef float f32x4 __attribute__((ext_vector_type(4)));
typedef unsigned short u16;
typedef u16 u16x8 __attribute__((ext_vector_type(8)));
typedef u16 u16x4 __attribute__((ext_vector_type(4)));

// ---------------- scalar helpers ----------------

__device__ inline float sigmoidf_(float x) { return 1.0f / (1.0f + expf(-x)); }

__device__ inline u16 f2bf(float f) {  // RNE float->bf16
    unsigned u = __builtin_bit_cast(unsigned, f);
    u = u + 0x7FFFu + ((u >> 16) & 1u);
    return (u16)(u >> 16);
}
__device__ inline float bf2f(u16 h) {
    return __builtin_bit_cast(float, (unsigned)h << 16);
}

// logmap0 o proj o expmap0 composite scale
__device__ inline float tangentize_scale(float n) {
    float n1 = fmaxf(n, EPSF);
    float m = fminf(tanhf(n1), MAXN);
    return atanhf(m) / n1;
}
__device__ inline float expproj_scale(float n) {
    float n1 = fmaxf(n, EPSF);
    return fminf(tanhf(n1), MAXN) / n1;
}

__device__ inline float blockReduceSum(float v) {
    __shared__ float sm[8];
    __syncthreads();
    #pragma unroll
    for (int off = 32; off > 0; off >>= 1) v += __shfl_down(v, off, 64);
    int w = threadIdx.x >> 6, lane = threadIdx.x & 63;
    if (lane == 0) sm[w] = v;
    __syncthreads();
    int nw = (blockDim.x + 63) >> 6;
    if (threadIdx.x == 0) {
        float r = sm[0];
        for (int i = 1; i < nw; ++i) r += sm[i];
        sm[0] = r;
    }
    __syncthreads();
    return sm[0];
}

// ---------------- precompute kernels ----------------

__global__ void cvt_f32_bf16(const float* __restrict__ s, u16* __restrict__ d, int n) {
    int i = (blockIdx.x * 256 + threadIdx.x) * 4;
    if (i < n) {
        float4 f = *reinterpret_cast<const float4*>(s + i);
        d[i + 0] = f2bf(f.x); d[i + 1] = f2bf(f.y);
        d[i + 2] = f2bf(f.z); d[i + 3] = f2bf(f.w);
    }
}

// sentb[t][b][k] = bf16( sent[b][t][k] * tangentize_scale(||sent[b][t]||) )
__global__ __launch_bounds__(256) void prep_sentb(const float* __restrict__ sent,
                                                  u16* __restrict__ sentb) {
    int bid = blockIdx.x;            // = b*75 + t
    int b = bid / T_, t = bid - b * T_;
    const float* src = sent + (size_t)bid * IN_;
    float v[3]; float ss = 0.f;
    #pragma unroll
    for (int e = 0; e < 3; ++e) { v[e] = src[threadIdx.x + e * 256]; ss += v[e] * v[e]; }
    float tot = blockReduceSum(ss);
    float sc = tangentize_scale(sqrtf(tot));
    u16* dst = sentb + ((size_t)t * B_ + b) * IN_;
    #pragma unroll
    for (int e = 0; e < 3; ++e) dst[threadIdx.x + e * 256] = f2bf(v[e] * sc);
}

__global__ __launch_bounds__(256) void xscale_kernel(const float* __restrict__ x,
                                                     float* __restrict__ xscale) {
    int row = blockIdx.x;
    const float* p = x + (size_t)row * IN_;
    float s = 0.f;
    for (int k = threadIdx.x; k < IN_; k += 256) { float v = p[k]; s += v * v; }
    float tot = blockReduceSum(s);
    if (threadIdx.x == 0) xscale[row] = tangentize_scale(sqrtf(tot));
}

__global__ void tf_kernel(const float* __restrict__ x, float* __restrict__ tf) {
    int b = blockIdx.x;
    float v = (threadIdx.x < T_) ? x[(size_t)b * T_ + threadIdx.x] : 0.f;
    float tot = blockReduceSum(v * v);
    float s = expproj_scale(sqrtf(tot));
    if (threadIdx.x < T_) tf[(size_t)b * T_ + threadIdx.x] = s * v;
}

// ---------------- XU GEMM (t-major): XU[t*1024+b][g] = xt @ U_all^T + b_U + b_all ----------
template<int F32SRC>
__global__ __launch_bounds__(256) void xu_gemm(const void* __restrict__ Asrc,
    const float* __restrict__ xscale, const u16* __restrict__ W,
    const float* __restrict__ b1, const float* __restrict__ b2, u16* __restrict__ C)
{
    __shared__ __align__(16) unsigned char As[128 * 128];
    __shared__ __align__(16) unsigned char Ws[128 * 128];
    int bid = (int)blockIdx.x;
    bid = (bid & 7) * ((int)gridDim.x >> 3) + (bid >> 3);   // 9600 % 8 == 0: bijective
    const int bn = (bid % 16) * 128;
    const int bm = (bid / 16) * 128;
    const int tq = bm >> 10;
    const int b0 = bm & 1023;

    const int tid = threadIdx.x;
    const int lane = tid & 63;
    const int wid = tid >> 6;
    const int wr = wid >> 1, wc = wid & 1;
    const int l15 = lane & 15, l4 = lane >> 4;

    f32x4 acc[4][4] = {};

    for (int k0 = 0; k0 < IN_; k0 += 64) {
        __syncthreads();
        #pragma unroll
        for (int c = 0; c < 4; ++c) {
            int ch = c * 256 + tid;
            int r = ch >> 3, q = ch & 7;
            unsigned off = (unsigned)(r * 128 + ((q ^ (r & 7)) * 16));
            if (F32SRC) {
                int b = b0 + r;
                const float* src = (const float*)Asrc + ((size_t)b * T_ + tq) * IN_ + k0 + q * 8;
                float rs = xscale[(size_t)b * T_ + tq];
                float4 f0 = *reinterpret_cast<const float4*>(src);
                float4 f1 = *reinterpret_cast<const float4*>(src + 4);
                u16x8 v;
                v[0] = f2bf(f0.x * rs); v[1] = f2bf(f0.y * rs);
                v[2] = f2bf(f0.z * rs); v[3] = f2bf(f0.w * rs);
                v[4] = f2bf(f1.x * rs); v[5] = f2bf(f1.y * rs);
                v[6] = f2bf(f1.z * rs); v[7] = f2bf(f1.w * rs);
                *reinterpret_cast<u16x8*>(As + off) = v;
            } else {
                const u16* src = (const u16*)Asrc + (size_t)(bm + r) * IN_ + k0 + q * 8;
                *reinterpret_cast<u16x8*>(As + off) = *reinterpret_cast<const u16x8*>(src);
            }
        }
        #pragma unroll
        for (int c = 0; c < 4; ++c) {
            int ch = c * 256 + tid;
            int r = ch >> 3, q = ch & 7;
            unsigned off = (unsigned)(r * 128 + ((q ^ (r & 7)) * 16));
            const u16* src = W + (size_t)(bn + r) * IN_ + k0 + q * 8;
            *reinterpret_cast<u16x8*>(Ws + off) = *reinterpret_cast<const u16x8*>(src);
        }
        __syncthreads();
        #pragma unroll
        for (int ks = 0; ks < 2; ++ks) {
            bf16x8 af[4], bf[4];
            #pragma unroll
            for (int m = 0; m < 4; ++m) {
                int r = wr * 64 + m * 16 + l15;
                af[m] = *reinterpret_cast<const bf16x8*>(As + r * 128 + (((ks * 4 + l4) ^ (r & 7)) * 16));
            }
            #pragma unroll
            for (int n = 0; n < 4; ++n) {
                int r = wc * 64 + n * 16 + l15;
                bf[n] = *reinterpret_cast<const bf16x8*>(Ws + r * 128 + (((ks * 4 + l4) ^ (r & 7)) * 16));
            }
            #pragma unroll
            for (int m = 0; m < 4; ++m)
                #pragma unroll
                for (int n = 0; n < 4; ++n)
                    acc[m][n] = __builtin_amdgcn_mfma_f32_16x16x32_bf16(af[m], bf[n], acc[m][n], 0, 0, 0);
        }
    }

    #pragma unroll
    for (int m = 0; m < 4; ++m)
        #pragma unroll
        for (int n = 0; n < 4; ++n) {
            int col = bn + wc * 64 + n * 16 + l15;
            float bb = b1[col] + b2[col];
            #pragma unroll
            for (int v = 0; v < 4; ++v) {
                int row = bm + wr * 64 + m * 16 + l4 * 4 + v;
                C[(size_t)row * G_ + col] = f2bf(acc[m][n][v] + bb);
            }
        }
}

// ---------------- grid-synced persistent kernel ----------------
// 256 blocks x 512 thr (8 waves: m = wid&3, nh = wid>>2).
// Block (bt, ct): rows r0..r0+63, h-cols j0..j0+31 -> gate cols {g*512+j0..} + cs1 cols.
// Weights col-partitioned: per-XCD L2 working set ~320 KB (encoder).
// Raw bf16 state (double-buffered), norm scale applied to f32 accumulators.

__global__ __launch_bounds__(512) void persistent2(
    const u16* __restrict__ XU, const float* __restrict__ tf_g,
    const u16* __restrict__ Wall, const u16* __restrict__ Wd, const float* __restrict__ bd,
    const u16* __restrict__ Wih, const u16* __restrict__ Whh,
    const float* __restrict__ b_ih, const float* __restrict__ b_hh,
    const u16* __restrict__ Wfcin, const float* __restrict__ b_fcin,
    const float* __restrict__ Wfco, const float* __restrict__ b_fco,
    const float* __restrict__ Wspan, const float* __restrict__ bspan,
    u16* __restrict__ hb0, u16* __restrict__ hb1,
    u16* __restrict__ cb0, u16* __restrict__ cb1,
    u16* __restrict__ ib0, u16* __restrict__ ib1,
    float* __restrict__ nrm_h, float* __restrict__ nrm_c,
    unsigned* __restrict__ bctr,
    float* __restrict__ out)
{
    const int bid = (int)blockIdx.x;
    const int bt = bid >> 4, ct = bid & 15;     // bid%8 == ct%8 -> weights XCD-pinned
    const int r0 = bt * 64, j0 = ct * 32;
    const int tid = threadIdx.x;
    const int lane = tid & 63;
    const int wid = tid >> 6;
    const int m = wid & 3, nh = wid >> 2;
    const int l15 = lane & 15, l4 = lane >> 4;

    u16* hb[2] = {hb0, hb1};
    u16* cb[2] = {cb0, cb1};
    u16* ib[2] = {ib0, ib1};

    __shared__ float shs[64], scs[64];
    __shared__ u16 gt[64 * 128];
    __shared__ u16 csd[64 * 32];

    int epoch = 0;
    auto gbar = [&]() {
        __syncthreads();
        if (tid == 0) {
            __threadfence();
            atomicAdd(bctr, 1u);
            unsigned tgt = (unsigned)(++epoch) * GRIDN;
            while (__hip_atomic_load(bctr, __ATOMIC_RELAXED, __HIP_MEMORY_SCOPE_AGENT) < tgt)
                __builtin_amdgcn_s_sleep(2);
            __threadfence();
        }
        __syncthreads();
    };

    const int prow = tid >> 3, pe0 = (tid & 7) * 4;   // pointwise mapping
    const int arow = r0 + m * 16 + l15;               // MFMA A row (global)

    // ================= encoder: 75 steps, 1 barrier each =================
    int p = 0;
    for (int t = 0; t < T_; ++t) {
        if (tid < 64) {
            shs[tid] = tangentize_scale(sqrtf(nrm_h[(size_t)t * B_ + r0 + tid]));
            scs[tid] = tangentize_scale(sqrtf(nrm_c[(size_t)t * B_ + r0 + tid]));
        }
        __syncthreads();

        const u16* hp = hb[p];
        const u16* cp = cb[p];
        const u16* aph = hp + (size_t)arow * 512 + l4 * 8;
        const u16* apc = cp + (size_t)arow * 512 + l4 * 8;

        f32x4 acc[5] = {};
        int colv[5];
        const u16* bp[5];
        #pragma unroll
        for (int i = 0; i < 5; ++i) {
            int q = nh * 5 + i;
            if (q < 8) { colv[i] = (q >> 1) * 512 + j0 + (q & 1) * 16 + l15;
                         bp[i] = Wall + (size_t)colv[i] * 512 + l4 * 8; }
            else       { colv[i] = j0 + (q - 8) * 16 + l15;
                         bp[i] = Wd + (size_t)colv[i] * 512 + l4 * 8; }
        }
        #pragma unroll 4
        for (int kc = 0; kc < 16; ++kc) {
            bf16x8 a = *reinterpret_cast<const bf16x8*>(aph + kc * 32);
            bf16x8 ac = a;
            if (nh) ac = *reinterpret_cast<const bf16x8*>(apc + kc * 32);
            #pragma unroll
            for (int i = 0; i < 5; ++i) {
                bf16x8 b = *reinterpret_cast<const bf16x8*>(bp[i] + kc * 32);
                bf16x8 aop = (i >= 3 && nh) ? ac : a;
                acc[i] = __builtin_amdgcn_mfma_f32_16x16x32_bf16(aop, b, acc[i], 0, 0, 0);
            }
        }
        // epilogue -> LDS (scale accumulators by per-row tangent scale)
        #pragma unroll
        for (int i = 0; i < 5; ++i) {
            int q = nh * 5 + i;
            int col = colv[i];
            #pragma unroll
            for (int v = 0; v < 4; ++v) {
                int lr = m * 16 + l4 * 4 + v;
                if (q < 8) {
                    float val = acc[i][v] * shs[lr]
                              + bf2f(XU[((size_t)t * B_ + r0 + lr) * G_ + col]);
                    gt[lr * 128 + (q >> 1) * 32 + (q & 1) * 16 + l15] = f2bf(sigmoidf_(val));
                } else {
                    float val = acc[i][v] * scs[lr] + bd[col];
                    csd[lr * 32 + (q - 8) * 16 + l15] = f2bf(tanhf(val));
                }
            }
        }
        __syncthreads();
        // pointwise: 4 elems/thread on own col-slice
        {
            float scr = scs[prow];
            float ts = tf_g[(size_t)(r0 + prow) * T_ + t];
            u16x4 f4 = *reinterpret_cast<const u16x4*>(&gt[prow * 128 + 0 + pe0]);
            u16x4 i4 = *reinterpret_cast<const u16x4*>(&gt[prow * 128 + 32 + pe0]);
            u16x4 o4 = *reinterpret_cast<const u16x4*>(&gt[prow * 128 + 64 + pe0]);
            u16x4 m4 = *reinterpret_cast<const u16x4*>(&gt[prow * 128 + 96 + pe0]);
            u16x4 c14 = *reinterpret_cast<const u16x4*>(&csd[prow * 32 + pe0]);
            u16x4 cr4 = *reinterpret_cast<const u16x4*>(cp + (size_t)(r0 + prow) * 512 + j0 + pe0);
            u16x4 hw, cw;
            float s2h = 0.f, s2c = 0.f;
            #pragma unroll
            for (int e = 0; e < 4; ++e) {
                float f = bf2f(f4[e]), ii = bf2f(i4[e]), o = bf2f(o4[e]), cm = bf2f(m4[e]);
                float c1 = bf2f(c14[e]);
                float ctv = scr * bf2f(cr4[e]);
                float cadj = ctv - c1 + c1 * ts;
                float cn = f * cadj + ii * cm;
                float hn = o * tanhf(cn);
                s2c += cn * cn; s2h += hn * hn;
                cw[e] = f2bf(cn); hw[e] = f2bf(hn);
            }
            *reinterpret_cast<u16x4*>(hb[p ^ 1] + (size_t)(r0 + prow) * 512 + j0 + pe0) = hw;
            *reinterpret_cast<u16x4*>(cb[p ^ 1] + (size_t)(r0 + prow) * 512 + j0 + pe0) = cw;
            #pragma unroll
            for (int off = 1; off < 8; off <<= 1) {
                s2h += __shfl_xor(s2h, off); s2c += __shfl_xor(s2c, off);
            }
            if ((lane & 7) == 0) {
                atomicAdd(&nrm_h[(size_t)(t + 1) * B_ + r0 + prow], s2h);
                atomicAdd(&nrm_c[(size_t)(t + 1) * B_ + r0 + prow], s2c);
            }
        }
        gbar();
        p ^= 1;
    }

    // ================= transition: hx = proj(tangent h), cx likewise ============
    {
        float n2h = nrm_h[(size_t)T_ * B_ + r0 + prow];
        float n2c = nrm_c[(size_t)T_ * B_ + r0 + prow];
        float nhv = sqrtf(n2h), ncv = sqrtf(n2c);
        float sh = tangentize_scale(nhv), sc = tangentize_scale(ncv);
        float tnh = sh * nhv, tnc = sc * ncv;
        float Sh = sh * (tnh > MAXN ? MAXN / tnh : 1.f);
        float Sc = sc * (tnc > MAXN ? MAXN / tnc : 1.f);
        u16x4 h4 = *reinterpret_cast<const u16x4*>(hb[p] + (size_t)(r0 + prow) * 512 + j0 + pe0);
        u16x4 c4 = *reinterpret_cast<const u16x4*>(cb[p] + (size_t)(r0 + prow) * 512 + j0 + pe0);
        u16x4 hw, cw;
        #pragma unroll
        for (int e = 0; e < 4; ++e) {
            hw[e] = f2bf(Sh * bf2f(h4[e]));
            cw[e] = f2bf(Sc * bf2f(c4[e]));
        }
        *reinterpret_cast<u16x4*>(hb[0] + (size_t)(r0 + prow) * 512 + j0 + pe0) = hw;
        *reinterpret_cast<u16x4*>(cb[0] + (size_t)(r0 + prow) * 512 + j0 + pe0) = cw;
    }
    gbar();

    // span softmax (ct==0 blocks)
    if (ct == 0 && tid < 256) {
        int row = tid >> 2, cl = tid & 3;
        float sum = 0.f;
        const u16* hx = hb[0] + (size_t)(r0 + row) * 512;
        for (int k = 0; k < 512; ++k) sum += bf2f(hx[k]) * Wspan[cl * 512 + k];
        sum += bspan[cl];
        float mx = sum;
        mx = fmaxf(mx, __shfl_xor(mx, 1));
        mx = fmaxf(mx, __shfl_xor(mx, 2));
        float ex = expf(sum - mx);
        float den = ex + __shfl_xor(ex, 1);
        den += __shfl_xor(den, 2);
        out[(size_t)(r0 + row) * 4 + cl] = ex / den;
    }

    // ================= decoder: 10 steps, 2 barriers each =================
    int pd = 0;
    for (int s = 0; s < 10; ++s) {
        const u16* ip = ib[pd];
        const u16* hp = hb[pd];
        const u16* apI = ip + (size_t)arow * IN_ + l4 * 8;
        const u16* apH = hp + (size_t)arow * 512 + l4 * 8;

        f32x4 dacc[4] = {};
        int colD[4];
        const u16* bpI[4];
        const u16* bpH[4];
        #pragma unroll
        for (int i = 0; i < 4; ++i) {
            int q = nh * 4 + i;
            colD[i] = (q >> 1) * 512 + j0 + (q & 1) * 16 + l15;   // torch order i,f,g,o
            bpI[i] = Wih + (size_t)colD[i] * IN_ + l4 * 8;
            bpH[i] = Whh + (size_t)colD[i] * 512 + l4 * 8;
        }
        #pragma unroll 4
        for (int kc = 0; kc < 24; ++kc) {
            bf16x8 a = *reinterpret_cast<const bf16x8*>(apI + kc * 32);
            #pragma unroll
            for (int i = 0; i < 4; ++i) {
                bf16x8 b = *reinterpret_cast<const bf16x8*>(bpI[i] + kc * 32);
                dacc[i] = __builtin_amdgcn_mfma_f32_16x16x32_bf16(a, b, dacc[i], 0, 0, 0);
            }
        }
        #pragma unroll 4
        for (int kc = 0; kc < 16; ++kc) {
            bf16x8 a = *reinterpret_cast<const bf16x8*>(apH + kc * 32);
            #pragma unroll
            for (int i = 0; i < 4; ++i) {
                bf16x8 b = *reinterpret_cast<const bf16x8*>(bpH[i] + kc * 32);
                dacc[i] = __builtin_amdgcn_mfma_f32_16x16x32_bf16(a, b, dacc[i], 0, 0, 0);
            }
        }
        #pragma unroll
        for (int i = 0; i < 4; ++i) {
            int q = nh * 4 + i;
            float bb = b_ih[colD[i]] + b_hh[colD[i]];
            #pragma unroll
            for (int v = 0; v < 4; ++v) {
                int lr = m * 16 + l4 * 4 + v;
                gt[lr * 128 + (q >> 1) * 32 + (q & 1) * 16 + l15] = f2bf(dacc[i][v] + bb);
            }
        }
        __syncthreads();
        // pointwise LSTM
        {
            u16x4 i4 = *reinterpret_cast<const u16x4*>(&gt[prow * 128 + 0 + pe0]);
            u16x4 f4 = *reinterpret_cast<const u16x4*>(&gt[prow * 128 + 32 + pe0]);
            u16x4 g4 = *reinterpret_cast<const u16x4*>(&gt[prow * 128 + 64 + pe0]);
            u16x4 o4 = *reinterpret_cast<const u16x4*>(&gt[prow * 128 + 96 + pe0]);
            u16x4 cr4 = *reinterpret_cast<const u16x4*>(cb[pd] + (size_t)(r0 + prow) * 512 + j0 + pe0);
            u16x4 hw, cw;
            #pragma unroll
            for (int e = 0; e < 4; ++e) {
                float ii = sigmoidf_(bf2f(i4[e]));
                float ff = sigmoidf_(bf2f(f4[e]));
                float gg = tanhf(bf2f(g4[e]));
                float oo = sigmoidf_(bf2f(o4[e]));
                float cn = ff * bf2f(cr4[e]) + ii * gg;
                float hn = oo * tanhf(cn);
                cw[e] = f2bf(cn); hw[e] = f2bf(hn);
            }
            *reinterpret_cast<u16x4*>(hb[pd ^ 1] + (size_t)(r0 + prow) * 512 + j0 + pe0) = hw;
            *reinterpret_cast<u16x4*>(cb[pd ^ 1] + (size_t)(r0 + prow) * 512 + j0 + pe0) = cw;
        }
        gbar();

        // fc_in (skip on last step) + out2
        const u16* hp2 = hb[pd ^ 1];
        if (s < 9) {
            const u16* ap2 = hp2 + (size_t)arow * 512 + l4 * 8;
            f32x4 facc[3] = {};
            int nf = nh ? 1 : 2;
            int colF[3];
            const u16* bpF[3];
            #pragma unroll
            for (int i = 0; i < 3; ++i) {
                int q = nh * 2 + i;
                colF[i] = ct * 48 + q * 16 + l15;
                bpF[i] = Wfcin + (size_t)colF[i] * 512 + l4 * 8;
            }
            #pragma unroll 4
            for (int kc = 0; kc < 16; ++kc) {
                bf16x8 a = *reinterpret_cast<const bf16x8*>(ap2 + kc * 32);
                for (int i = 0; i < nf; ++i) {
                    bf16x8 b = *reinterpret_cast<const bf16x8*>(bpF[i] + kc * 32);
                    facc[i] = __builtin_amdgcn_mfma_f32_16x16x32_bf16(a, b, facc[i], 0, 0, 0);
                }
            }
            for (int i = 0; i < nf; ++i) {
                float bb = b_fcin[colF[i]];
                #pragma unroll
                for (int v = 0; v < 4; ++v) {
                    int lr = m * 16 + l4 * 4 + v;
                    ib[pd ^ 1][(size_t)(r0 + lr) * IN_ + colF[i]] = f2bf(fmaxf(facc[i][v] + bb, 0.f));
                }
            }
        }
        if (ct == 15 && tid < 128) {
            int row = tid >> 1, cl = tid & 1;
            const u16* hx = hp2 + (size_t)(r0 + row) * 512;
            float sum = 0.f;
            for (int k = 0; k < 512; ++k) sum += bf2f(hx[k]) * Wfco[cl * 512 + k];
            sum += b_fco[cl];
            float o2 = __shfl_xor(sum, 1);
            float mx = fmaxf(sum, o2);
            float ex = expf(sum - mx), eo = expf(o2 - mx);
            out[4096 + (size_t)(r0 + row) * 20 + s * 2 + cl] = ex / (ex + eo);
        }
        gbar();
        pd ^= 1;
    }
}

// ---------------- launch ----------------

extern "C" void kernel_launch(void* const* d_in, const int* in_sizes, int n_in,
                              void* d_out, int out_size, void* d_ws, size_t ws_size,
                              hipStream_t stream) {
    (void)in_sizes; (void)n_in; (void)out_size;
    const float* sent    = (const float*)d_in[0];
    const float* timef   = (const float*)d_in[1];
    const float* Wd      = (const float*)d_in[2];
    const float* bd      = (const float*)d_in[3];
    const float* W_all   = (const float*)d_in[4];
    const float* b_all   = (const float*)d_in[5];
    const float* U_all   = (const float*)d_in[6];
    const float* b_U     = (const float*)d_in[7];
    const float* W_ih    = (const float*)d_in[8];
    const float* b_ih    = (const float*)d_in[9];
    const float* W_hh    = (const float*)d_in[10];
    const float* b_hh    = (const float*)d_in[11];
    const float* W_fc_in = (const float*)d_in[12];
    const float* b_fc_in = (const float*)d_in[13];
    const float* W_fc_out= (const float*)d_in[14];
    const float* b_fc_out= (const float*)d_in[15];
    const float* W_span  = (const float*)d_in[16];
    const float* b_span  = (const float*)d_in[17];
    float* out = (float*)d_out;

    char* ws = (char*)d_ws;
    size_t off = 0;
    auto alloc = [&](size_t bytes) -> void* {
        void* p = ws + off; off = (off + bytes + 255) & ~(size_t)255; return p;
    };
    float* tf     = (float*)alloc((size_t)B_ * T_ * 4);
    u16* Wall_b   = (u16*)alloc((size_t)G_ * H_ * 2);
    u16* Uall_b   = (u16*)alloc((size_t)G_ * IN_ * 2);
    u16* Wd_b     = (u16*)alloc((size_t)H_ * H_ * 2);
    u16* Wih_b    = (u16*)alloc((size_t)G_ * IN_ * 2);
    u16* Whh_b    = (u16*)alloc((size_t)G_ * H_ * 2);
    u16* Wfcin_b  = (u16*)alloc((size_t)IN_ * H_ * 2);
    float* xscale = (float*)alloc((size_t)B_ * T_ * 4);
    u16* hbuf0    = (u16*)alloc((size_t)B_ * H_ * 2);
    u16* hbuf1    = (u16*)alloc((size_t)B_ * H_ * 2);
    u16* cbuf0    = (u16*)alloc((size_t)B_ * H_ * 2);
    u16* cbuf1    = (u16*)alloc((size_t)B_ * H_ * 2);
    u16* ibuf0    = (u16*)alloc((size_t)B_ * IN_ * 2);
    u16* ibuf1    = (u16*)alloc((size_t)B_ * IN_ * 2);
    float* nrm_h  = (float*)alloc((size_t)(T_ + 1) * B_ * 4);
    float* nrm_c  = (float*)alloc((size_t)(T_ + 1) * B_ * 4);
    unsigned* bctr = (unsigned*)alloc(256);
    u16* XU       = (u16*)alloc((size_t)B_ * T_ * G_ * 2);
    u16* sentb    = (u16*)alloc((size_t)B_ * T_ * IN_ * 2);
    bool pathA = (off <= ws_size);

    // per-launch (and per-replay) re-init: atomics/barrier accumulate otherwise
    hipMemsetAsync(bctr, 0, 256, stream);
    hipMemsetAsync(nrm_h, 0, (size_t)(T_ + 1) * B_ * 4, stream);
    hipMemsetAsync(nrm_c, 0, (size_t)(T_ + 1) * B_ * 4, stream);
    hipMemsetAsync(hbuf0, 0, (size_t)B_ * H_ * 2, stream);
    hipMemsetAsync(cbuf0, 0, (size_t)B_ * H_ * 2, stream);
    hipMemsetAsync(ibuf0, 0, (size_t)B_ * IN_ * 2, stream);

    auto cvt = [&](const float* s, u16* d, int n) {
        cvt_f32_bf16<<<(n / 4 + 255) / 256, 256, 0, stream>>>(s, d, n);
    };
    cvt(W_all, Wall_b, G_ * H_);
    cvt(U_all, Uall_b, G_ * IN_);
    cvt(Wd, Wd_b, H_ * H_);
    cvt(W_ih, Wih_b, G_ * IN_);
    cvt(W_hh, Whh_b, G_ * H_);
    cvt(W_fc_in, Wfcin_b, IN_ * H_);

    tf_kernel<<<B_, 128, 0, stream>>>(timef, tf);

    if (pathA) {
        prep_sentb<<<B_ * T_, 256, 0, stream>>>(sent, sentb);
        xu_gemm<0><<<(B_ * T_ / 128) * (G_ / 128), 256, 0, stream>>>(
            sentb, nullptr, Uall_b, b_all, b_U, XU);
    } else {
        xscale_kernel<<<B_ * T_, 256, 0, stream>>>(sent, xscale);
        xu_gemm<1><<<(B_ * T_ / 128) * (G_ / 128), 256, 0, stream>>>(
            sent, xscale, Uall_b, b_all, b_U, XU);
    }

    persistent2<<<GRIDN, 512, 0, stream>>>(
        XU, tf, Wall_b, Wd_b, bd, Wih_b, Whh_b, b_ih, b_hh,
        Wfcin_b, b_fc_in, W_fc_out, b_fc_out, W_span, b_span,
        hbuf0, hbuf1, cbuf0, cbuf1, ibuf0, ibuf1,
        nrm_h, nrm_c, bctr, out);
}